// Round 1
// baseline (2848.936 us; speedup 1.0000x reference)
//
#include <hip/hip_runtime.h>

#define NN 131072
#define BB 32

struct LevelParams {
  const float* u[12];
  int t_off[12];   // float offsets into workspace
  int r[12];
  int rpad[12];
  int lb[12];      // log2(bsz); bsz = 32 << (11 - level) = 2^(16-level)
};

// ---------------- t-pass: t[seg][n][j] = sum_{s in seg} U[s][j] * x[n][s] --------
// grid: 12 levels * 128 chunks (1024 rows each), 256 threads
__global__ __launch_bounds__(256, 3)
void tpass_kernel(const float* __restrict__ x, float* __restrict__ t,
                  LevelParams P) {
  __shared__ float xT[128 * 36];   // [s][n], padded to 36 for bank spread + b128 align
  __shared__ float Ut[128 * 64];   // [s][rpad], zero-filled j>=r

  const int bid = blockIdx.x;
  const int l = bid >> 7;
  const int chunk = bid & 127;
  const int tid = threadIdx.x;

  const float* __restrict__ u = P.u[l];
  const int r = P.r[l];
  const int rpad = P.rpad[l];
  const int lb = P.lb[l];
  float* __restrict__ tl = t + P.t_off[l];

  const int G = rpad >> 3;           // active j-groups
  const int split = tid >> 5;        // 0..7 : row-split within 128-row subtile
  const int lane32 = tid & 31;
  const int n0 = (lane32 >> 3) << 3; // 0,8,16,24
  const int jg = lane32 & 7;
  const int j0 = jg << 3;
  const bool active = (jg < G);

  float acc[8][8];
  #pragma unroll
  for (int a = 0; a < 8; a++)
    #pragma unroll
    for (int b = 0; b < 8; b++) acc[a][b] = 0.f;

  const int Rc = chunk << 10;
  const int r4 = rpad >> 2;
  const int uslots = 32 * rpad;      // (128*rpad)/4 float4 slots

  for (int sub = 0; sub < 8; sub++) {
    const int s0 = Rc + (sub << 7);
    // stage x transposed: xT[ss][n]
    #pragma unroll
    for (int rep = 0; rep < 16; rep++) {
      int idx = rep * 256 + tid;
      int ss = idx & 127;
      int n = idx >> 7;
      xT[ss * 36 + n] = x[n * NN + s0 + ss];
    }
    // stage U rows (zero-pad j>=r)
    for (int slot = tid; slot < uslots; slot += 256) {
      int row = slot / r4;
      int c4 = slot - row * r4;
      int j = c4 << 2;
      float4 v;
      if (j < r) v = *(const float4*)&u[(s0 + row) * r + j];
      else       v = make_float4(0.f, 0.f, 0.f, 0.f);
      *(float4*)&Ut[row * rpad + j] = v;
    }
    __syncthreads();

    if (active) {
      const int sl0 = split << 4;
      #pragma unroll 4
      for (int ss = 0; ss < 16; ss++) {
        const int sl = sl0 + ss;
        float4 xa = *(const float4*)&xT[sl * 36 + n0];
        float4 xb = *(const float4*)&xT[sl * 36 + n0 + 4];
        float4 ua = *(const float4*)&Ut[sl * rpad + j0];
        float4 ub = *(const float4*)&Ut[sl * rpad + j0 + 4];
        float xs[8] = {xa.x, xa.y, xa.z, xa.w, xb.x, xb.y, xb.z, xb.w};
        float us[8] = {ua.x, ua.y, ua.z, ua.w, ub.x, ub.y, ub.z, ub.w};
        #pragma unroll
        for (int a = 0; a < 8; a++)
          #pragma unroll
          for (int b = 0; b < 8; b++)
            acc[a][b] += xs[a] * us[b];
      }
      // flush when this split's rows leave the current segment (or at end)
      int grow = s0 + (split << 4);
      int gseg = grow >> lb;
      bool fl = (sub == 7) || (((grow + 128) >> lb) != gseg);
      if (fl) {
        float* base = tl + (gseg * 32 + n0) * rpad + j0;
        #pragma unroll
        for (int a = 0; a < 8; a++)
          #pragma unroll
          for (int b = 0; b < 8; b++) {
            atomicAdd(base + a * rpad + b, acc[a][b]);
            acc[a][b] = 0.f;
          }
      }
    }
    __syncthreads();
  }
}

// ---------------- y-pass: out[n][i] = leaf(i) + s2 * sum_l sum_j U_l[i][j]*t_l[sib][n][j]
// grid: N/256 WGs, 256 threads; thread tile = 8 rows x 4 batches
__global__ __launch_bounds__(256, 2)
void ypass_kernel(const float* __restrict__ x,
                  const float* __restrict__ leaf,
                  const float* __restrict__ scale,
                  const float* __restrict__ t,
                  float* __restrict__ out,
                  LevelParams P) {
  __shared__ float smem[17664];  // 70656 B: phase A uses 9216 (xT) + 8448 (Lb)

  const int bid = blockIdx.x;
  const int tid = threadIdx.x;
  const int R0 = bid << 8;         // 256 rows per WG
  const int ig = tid >> 3;         // 0..31  -> i0l = ig*8
  const int ng = tid & 7;          // 0..7   -> n0 = ng*4
  const int i0l = ig << 3;
  const int n0 = ng << 2;

  const float sc = scale[0];
  const float s2 = sc * sc;

  float acc[8][4];
  #pragma unroll
  for (int k = 0; k < 8; k++)
    #pragma unroll
    for (int m = 0; m < 4; m++) acc[k][m] = 0.f;

  // ---- Phase A: leaf block-diagonal ----
  {
    float* xT = smem;           // [256][36]
    float* Lb = smem + 9216;    // [8][32][33]
    #pragma unroll 4
    for (int rep = 0; rep < 32; rep++) {
      xT[tid * 36 + rep] = x[rep * NN + R0 + tid];
    }
    const float* lbase = leaf + (R0 >> 5) * 1024;
    for (int slot = tid; slot < 2048; slot += 256) {
      int flat = slot << 2;
      float4 v = *(const float4*)&lbase[flat];
      int b = flat >> 10;
      int tt_ = (flat >> 5) & 31;
      int s = flat & 31;
      float* dst = &Lb[b * 1056 + tt_ * 33 + s];
      dst[0] = v.x; dst[1] = v.y; dst[2] = v.z; dst[3] = v.w;
    }
    __syncthreads();
    const int bl = ig >> 2;
    const int irow0 = (ig & 3) << 3;
    #pragma unroll 4
    for (int s = 0; s < 32; s++) {
      float4 xv = *(const float4*)&xT[(bl * 32 + s) * 36 + n0];
      float xs[4] = {xv.x, xv.y, xv.z, xv.w};
      #pragma unroll
      for (int k = 0; k < 8; k++) {
        float L = Lb[bl * 1056 + (irow0 + k) * 33 + s];
        #pragma unroll
        for (int m = 0; m < 4; m++) acc[k][m] += L * xs[m];
      }
    }
    __syncthreads();
  }

  // ---- Phase B: levels ----
  float* ttl = smem;          // up to 6144 floats (sibling t, pre-scaled by s2)
  float* Uc  = smem + 6144;   // [256][8]
  for (int l = 0; l < 12; l++) {
    const float* __restrict__ u = P.u[l];
    const int r = P.r[l], rpad = P.rpad[l], lb = P.lb[l];
    const float* tl = t + P.t_off[l];
    const int segfloats = 32 * rpad;
    const int span_sh = (lb >= 8) ? 0 : (8 - lb);   // segments spanned by 256 rows
    const int total4 = (segfloats << span_sh) >> 2;
    const int bseg = R0 >> lb;
    for (int idx4 = tid; idx4 < total4; idx4 += 256) {
      int flat = idx4 << 2;
      int k = flat / segfloats;
      int rem = flat - k * segfloats;
      int sib = (bseg + k) ^ 1;
      float4 v = *(const float4*)&tl[sib * segfloats + rem];
      v.x *= s2; v.y *= s2; v.z *= s2; v.w *= s2;
      *(float4*)&ttl[flat] = v;
    }
    __syncthreads();
    const int kseg = i0l >> lb;   // local segment of this thread's rows
    const float* ttb = ttl + kseg * segfloats + n0 * rpad;
    const int nj = rpad >> 3;
    for (int jc = 0; jc < nj; jc++) {
      // stage Uc[256][8] (zero-pad j>=r)
      #pragma unroll
      for (int rep = 0; rep < 2; rep++) {
        int slot = rep * 256 + tid;
        int row = slot >> 1;
        int h = (slot & 1) << 2;
        int j = (jc << 3) + h;
        float4 v;
        if (j < r) v = *(const float4*)&u[(R0 + row) * r + j];
        else       v = make_float4(0.f, 0.f, 0.f, 0.f);
        *(float4*)&Uc[(row << 3) + h] = v;
      }
      __syncthreads();
      #pragma unroll
      for (int half = 0; half < 2; half++) {
        const int jb = (jc << 3) + (half << 2);
        float4 tv0 = *(const float4*)&ttb[0 * rpad + jb];
        float4 tv1 = *(const float4*)&ttb[1 * rpad + jb];
        float4 tv2 = *(const float4*)&ttb[2 * rpad + jb];
        float4 tv3 = *(const float4*)&ttb[3 * rpad + jb];
        #pragma unroll
        for (int k = 0; k < 8; k++) {
          float4 uv = *(const float4*)&Uc[((i0l + k) << 3) + (half << 2)];
          acc[k][0] += uv.x * tv0.x + uv.y * tv0.y + uv.z * tv0.z + uv.w * tv0.w;
          acc[k][1] += uv.x * tv1.x + uv.y * tv1.y + uv.z * tv1.z + uv.w * tv1.w;
          acc[k][2] += uv.x * tv2.x + uv.y * tv2.y + uv.z * tv2.z + uv.w * tv2.w;
          acc[k][3] += uv.x * tv3.x + uv.y * tv3.y + uv.z * tv3.z + uv.w * tv3.w;
        }
      }
      __syncthreads();
    }
  }

  // ---- epilogue: single write of y ----
  #pragma unroll
  for (int m = 0; m < 4; m++) {
    float4 o0 = make_float4(acc[0][m], acc[1][m], acc[2][m], acc[3][m]);
    float4 o1 = make_float4(acc[4][m], acc[5][m], acc[6][m], acc[7][m]);
    float* dst = out + (n0 + m) * NN + R0 + i0l;
    *(float4*)&dst[0] = o0;
    *(float4*)&dst[4] = o1;
  }
}

extern "C" void kernel_launch(void* const* d_in, const int* in_sizes, int n_in,
                              void* d_out, int out_size, void* d_ws, size_t ws_size,
                              hipStream_t stream) {
  const float* x     = (const float*)d_in[0];
  const float* leaf  = (const float*)d_in[1];
  const float* scale = (const float*)d_in[2];

  static const int RANKS[12] = {64,64,64,64,64,64,64,64,64,52,32,20};
  LevelParams P;
  int off = 0;
  for (int l = 0; l < 12; l++) {
    P.u[l] = (const float*)d_in[3 + l];
    P.r[l] = RANKS[l];
    P.rpad[l] = (RANKS[l] + 7) & ~7;
    P.lb[l] = 16 - l;
    P.t_off[l] = off;
    off += (2 << l) * 32 * P.rpad[l];
  }
  size_t tbytes = (size_t)off * sizeof(float);
  hipMemsetAsync(d_ws, 0, tbytes, stream);

  float* t = (float*)d_ws;
  tpass_kernel<<<dim3(12 * 128), dim3(256), 0, stream>>>(x, t, P);
  ypass_kernel<<<dim3(NN / 256), dim3(256), 0, stream>>>(x, leaf, scale, t,
                                                         (float*)d_out, P);
}

// Round 2
// 674.540 us; speedup vs baseline: 4.2235x; 4.2235x over previous
//
#include <hip/hip_runtime.h>

#define NN 131072
#define BB 32

struct LevelParams {
  const float* u[12];
  int t_off[12];   // float offsets into workspace
  int r[12];
  int rpad[12];
  int lb[12];      // log2(bsz); bsz = 2^(16-level)
};

// ---------------- t-pass: t[seg][n][j] = sum_{s in seg} U[s][j] * x[n][s] --------
// grid: 12 levels * 128 chunks (1024 rows each), 256 threads. NO global atomics:
// cross-split combine via LDS tree; levels 0..6 write per-chunk partials
// (reduced by reduce_kernel), levels 7..11 write t directly (unique writer).
__global__ __launch_bounds__(256, 3)
void tpass_kernel(const float* __restrict__ x, float* __restrict__ t,
                  float* __restrict__ part, LevelParams P) {
  __shared__ float xT[128 * 36];   // [s][n], padded
  __shared__ float Ut[128 * 64];   // [s][rpad]; reused as 4x2048 reduction scratch

  const int bid = blockIdx.x;
  const int l = bid >> 7;
  const int chunk = bid & 127;
  const int tid = threadIdx.x;

  const float* __restrict__ u = P.u[l];
  const int r = P.r[l];
  const int rpad = P.rpad[l];
  const int lb = P.lb[l];
  float* __restrict__ tl = t + P.t_off[l];

  const int G = rpad >> 3;           // active j-groups
  const int split = tid >> 5;        // 0..7 : 16-row slice within 128-row window
  const int lane32 = tid & 31;
  const int n0 = (lane32 >> 3) << 3; // 0,8,16,24
  const int jg = lane32 & 7;
  const int j0 = jg << 3;
  const bool active = (jg < G);

  const int lg = (lb >= 7) ? 3 : (lb - 4);  // log2(splits per segment group)
  const int gsz = 1 << lg;

  float acc[8][8];
  #pragma unroll
  for (int a = 0; a < 8; a++)
    #pragma unroll
    for (int b = 0; b < 8; b++) acc[a][b] = 0.f;

  const int Rc = chunk << 10;
  const int r4 = rpad >> 2;
  const int uslots = 32 * rpad;      // (128*rpad)/4 float4 slots

  for (int sub = 0; sub < 8; sub++) {
    const int s0 = Rc + (sub << 7);
    // stage x transposed: xT[ss][n]
    #pragma unroll
    for (int rep = 0; rep < 16; rep++) {
      int idx = rep * 256 + tid;
      int ss = idx & 127;
      int n = idx >> 7;
      xT[ss * 36 + n] = x[n * NN + s0 + ss];
    }
    // stage U rows (zero-pad j>=r)
    for (int slot = tid; slot < uslots; slot += 256) {
      int row = slot / r4;
      int c4 = slot - row * r4;
      int j = c4 << 2;
      float4 v;
      if (j < r) v = *(const float4*)&u[(s0 + row) * r + j];
      else       v = make_float4(0.f, 0.f, 0.f, 0.f);
      *(float4*)&Ut[row * rpad + j] = v;
    }
    __syncthreads();

    if (active) {
      const int sl0 = split << 4;
      #pragma unroll 4
      for (int ss = 0; ss < 16; ss++) {
        const int sl = sl0 + ss;
        float4 xa = *(const float4*)&xT[sl * 36 + n0];
        float4 xb = *(const float4*)&xT[sl * 36 + n0 + 4];
        float4 ua = *(const float4*)&Ut[sl * rpad + j0];
        float4 ub = *(const float4*)&Ut[sl * rpad + j0 + 4];
        float xs[8] = {xa.x, xa.y, xa.z, xa.w, xb.x, xb.y, xb.z, xb.w};
        float us[8] = {ua.x, ua.y, ua.z, ua.w, ub.x, ub.y, ub.z, ub.w};
        #pragma unroll
        for (int a = 0; a < 8; a++)
          #pragma unroll
          for (int b = 0; b < 8; b++)
            acc[a][b] += xs[a] * us[b];
      }
    }

    // block-uniform flush: end of chunk, or the 128-row window ends a segment
    const bool fl = (sub == 7) || (((s0 + 128) >> lb) != (s0 >> lb));
    if (fl) {
      __syncthreads();   // all compute reads of Ut done before reusing as scratch
      // tree-reduce across the gsz splits that share each segment
      for (int h = gsz >> 1; h >= 1; h >>= 1) {
        const int sig = split & (gsz - 1);
        if (active && sig >= h && sig < (h << 1)) {
          int rid = split - h;                         // reader split id
          int slot = (rid >> lg) * h + (rid & (gsz - 1));  // 0..3
          float* dst = Ut + slot * 2048 + lane32;      // [(a*8+b)][lane32]
          #pragma unroll
          for (int a = 0; a < 8; a++)
            #pragma unroll
            for (int b = 0; b < 8; b++)
              dst[(a * 8 + b) * 32] = acc[a][b];
        }
        __syncthreads();
        if (active && (split & (gsz - 1)) < h) {
          int slot = (split >> lg) * h + (split & (gsz - 1));
          const float* src = Ut + slot * 2048 + lane32;
          #pragma unroll
          for (int a = 0; a < 8; a++)
            #pragma unroll
            for (int b = 0; b < 8; b++)
              acc[a][b] += src[(a * 8 + b) * 32];
        }
        __syncthreads();
      }
      // group leaders write the full 32 x rpad segment tile (unique writer)
      if (active && (split & (gsz - 1)) == 0) {
        const int grow = s0 + (split << 4);
        const int gseg = grow >> lb;
        float* outp = (lb >= 10) ? (part + (l * 128 + chunk) * 2048)
                                 : (tl + gseg * 32 * rpad);
        float* base = outp + n0 * rpad + j0;
        #pragma unroll
        for (int a = 0; a < 8; a++) {
          *(float4*)&base[a * rpad]     = make_float4(acc[a][0], acc[a][1], acc[a][2], acc[a][3]);
          *(float4*)&base[a * rpad + 4] = make_float4(acc[a][4], acc[a][5], acc[a][6], acc[a][7]);
        }
      }
      #pragma unroll
      for (int a = 0; a < 8; a++)
        #pragma unroll
        for (int b = 0; b < 8; b++) acc[a][b] = 0.f;
    }
    __syncthreads();
  }
}

// ---------------- reduce: t[l][seg] = sum over chunks of part tiles (levels 0..6)
// grid: 254 blocks (one per segment), 256 threads, 8 floats each
__global__ __launch_bounds__(256)
void reduce_kernel(const float* __restrict__ part, float* __restrict__ t,
                   LevelParams P) {
  int b = blockIdx.x;
  int l = 0, segs = 2;
  while (b >= segs) { b -= segs; l++; segs <<= 1; }   // l in 0..6, b = seg index
  const int nch = 64 >> l;                            // chunks per segment
  const int tid = threadIdx.x;
  const float* src = part + (size_t)(l * 128 + b * nch) * 2048 + tid * 8;
  float s0 = 0.f, s1 = 0.f, s2 = 0.f, s3 = 0.f, s4 = 0.f, s5 = 0.f, s6 = 0.f, s7 = 0.f;
  for (int k = 0; k < nch; k++) {
    float4 v0 = *(const float4*)&src[k * 2048];
    float4 v1 = *(const float4*)&src[k * 2048 + 4];
    s0 += v0.x; s1 += v0.y; s2 += v0.z; s3 += v0.w;
    s4 += v1.x; s5 += v1.y; s6 += v1.z; s7 += v1.w;
  }
  float* dst = t + P.t_off[l] + b * 2048 + tid * 8;
  *(float4*)dst = make_float4(s0, s1, s2, s3);
  *(float4*)&dst[4] = make_float4(s4, s5, s6, s7);
}

// ---------------- y-pass: out[n][i] = leaf(i) + s2 * sum_l sum_j U_l[i][j]*t_l[sib][n][j]
// grid: N/256 WGs, 256 threads; thread tile = 8 rows x 4 batches
__global__ __launch_bounds__(256, 2)
void ypass_kernel(const float* __restrict__ x,
                  const float* __restrict__ leaf,
                  const float* __restrict__ scale,
                  const float* __restrict__ t,
                  float* __restrict__ out,
                  LevelParams P) {
  __shared__ float smem[17664];  // 70656 B: phase A uses 9216 (xT) + 8448 (Lb)

  const int bid = blockIdx.x;
  const int tid = threadIdx.x;
  const int R0 = bid << 8;         // 256 rows per WG
  const int ig = tid >> 3;         // 0..31  -> i0l = ig*8
  const int ng = tid & 7;          // 0..7   -> n0 = ng*4
  const int i0l = ig << 3;
  const int n0 = ng << 2;

  const float sc = scale[0];
  const float s2 = sc * sc;

  float acc[8][4];
  #pragma unroll
  for (int k = 0; k < 8; k++)
    #pragma unroll
    for (int m = 0; m < 4; m++) acc[k][m] = 0.f;

  // ---- Phase A: leaf block-diagonal ----
  {
    float* xT = smem;           // [256][36]
    float* Lb = smem + 9216;    // [8][32][33]
    #pragma unroll 4
    for (int rep = 0; rep < 32; rep++) {
      xT[tid * 36 + rep] = x[rep * NN + R0 + tid];
    }
    const float* lbase = leaf + (R0 >> 5) * 1024;
    for (int slot = tid; slot < 2048; slot += 256) {
      int flat = slot << 2;
      float4 v = *(const float4*)&lbase[flat];
      int b = flat >> 10;
      int tt_ = (flat >> 5) & 31;
      int s = flat & 31;
      float* dst = &Lb[b * 1056 + tt_ * 33 + s];
      dst[0] = v.x; dst[1] = v.y; dst[2] = v.z; dst[3] = v.w;
    }
    __syncthreads();
    const int bl = ig >> 2;
    const int irow0 = (ig & 3) << 3;
    #pragma unroll 4
    for (int s = 0; s < 32; s++) {
      float4 xv = *(const float4*)&xT[(bl * 32 + s) * 36 + n0];
      float xs[4] = {xv.x, xv.y, xv.z, xv.w};
      #pragma unroll
      for (int k = 0; k < 8; k++) {
        float L = Lb[bl * 1056 + (irow0 + k) * 33 + s];
        #pragma unroll
        for (int m = 0; m < 4; m++) acc[k][m] += L * xs[m];
      }
    }
    __syncthreads();
  }

  // ---- Phase B: levels ----
  float* ttl = smem;          // up to 6144 floats (sibling t, pre-scaled by s2)
  float* Uc  = smem + 6144;   // [256][8]
  for (int l = 0; l < 12; l++) {
    const float* __restrict__ u = P.u[l];
    const int r = P.r[l], rpad = P.rpad[l], lb = P.lb[l];
    const float* tl = t + P.t_off[l];
    const int segfloats = 32 * rpad;
    const int span_sh = (lb >= 8) ? 0 : (8 - lb);   // segments spanned by 256 rows
    const int total4 = (segfloats << span_sh) >> 2;
    const int bseg = R0 >> lb;
    for (int idx4 = tid; idx4 < total4; idx4 += 256) {
      int flat = idx4 << 2;
      int k = flat / segfloats;
      int rem = flat - k * segfloats;
      int sib = (bseg + k) ^ 1;
      float4 v = *(const float4*)&tl[sib * segfloats + rem];
      v.x *= s2; v.y *= s2; v.z *= s2; v.w *= s2;
      *(float4*)&ttl[flat] = v;
    }
    __syncthreads();
    const int kseg = i0l >> lb;   // local segment of this thread's rows
    const float* ttb = ttl + kseg * segfloats + n0 * rpad;
    const int nj = rpad >> 3;
    for (int jc = 0; jc < nj; jc++) {
      // stage Uc[256][8] (zero-pad j>=r)
      #pragma unroll
      for (int rep = 0; rep < 2; rep++) {
        int slot = rep * 256 + tid;
        int row = slot >> 1;
        int h = (slot & 1) << 2;
        int j = (jc << 3) + h;
        float4 v;
        if (j < r) v = *(const float4*)&u[(R0 + row) * r + j];
        else       v = make_float4(0.f, 0.f, 0.f, 0.f);
        *(float4*)&Uc[(row << 3) + h] = v;
      }
      __syncthreads();
      #pragma unroll
      for (int half = 0; half < 2; half++) {
        const int jb = (jc << 3) + (half << 2);
        float4 tv0 = *(const float4*)&ttb[0 * rpad + jb];
        float4 tv1 = *(const float4*)&ttb[1 * rpad + jb];
        float4 tv2 = *(const float4*)&ttb[2 * rpad + jb];
        float4 tv3 = *(const float4*)&ttb[3 * rpad + jb];
        #pragma unroll
        for (int k = 0; k < 8; k++) {
          float4 uv = *(const float4*)&Uc[((i0l + k) << 3) + (half << 2)];
          acc[k][0] += uv.x * tv0.x + uv.y * tv0.y + uv.z * tv0.z + uv.w * tv0.w;
          acc[k][1] += uv.x * tv1.x + uv.y * tv1.y + uv.z * tv1.z + uv.w * tv1.w;
          acc[k][2] += uv.x * tv2.x + uv.y * tv2.y + uv.z * tv2.z + uv.w * tv2.w;
          acc[k][3] += uv.x * tv3.x + uv.y * tv3.y + uv.z * tv3.z + uv.w * tv3.w;
        }
      }
      __syncthreads();
    }
  }

  // ---- epilogue: single write of y ----
  #pragma unroll
  for (int m = 0; m < 4; m++) {
    float4 o0 = make_float4(acc[0][m], acc[1][m], acc[2][m], acc[3][m]);
    float4 o1 = make_float4(acc[4][m], acc[5][m], acc[6][m], acc[7][m]);
    float* dst = out + (n0 + m) * NN + R0 + i0l;
    *(float4*)&dst[0] = o0;
    *(float4*)&dst[4] = o1;
  }
}

extern "C" void kernel_launch(void* const* d_in, const int* in_sizes, int n_in,
                              void* d_out, int out_size, void* d_ws, size_t ws_size,
                              hipStream_t stream) {
  const float* x     = (const float*)d_in[0];
  const float* leaf  = (const float*)d_in[1];
  const float* scale = (const float*)d_in[2];

  static const int RANKS[12] = {64,64,64,64,64,64,64,64,64,52,32,20};
  LevelParams P;
  int off = 0;
  for (int l = 0; l < 12; l++) {
    P.u[l] = (const float*)d_in[3 + l];
    P.r[l] = RANKS[l];
    P.rpad[l] = (RANKS[l] + 7) & ~7;
    P.lb[l] = 16 - l;
    P.t_off[l] = off;
    off += (2 << l) * 32 * P.rpad[l];
  }

  float* t = (float*)d_ws;
  float* part = t + off;                 // 7 levels * 128 chunks * 2048 floats

  tpass_kernel<<<dim3(12 * 128), dim3(256), 0, stream>>>(x, t, part, P);
  reduce_kernel<<<dim3(254), dim3(256), 0, stream>>>(part, t, P);
  ypass_kernel<<<dim3(NN / 256), dim3(256), 0, stream>>>(x, leaf, scale, t,
                                                         (float*)d_out, P);
}